// Round 10
// baseline (334.001 us; speedup 1.0000x reference)
//
#include <hip/hip_runtime.h>
#include <math.h>

namespace {
constexpr int kT = 16;
constexpr int kH = 56;
constexpr int kW = 56;
constexpr int kCAll = 256;
constexpr int kPlane = kH * kW;      // 3136
constexpr int kPlane4 = kPlane / 4;  // 784
}

// Gate layout (fp32, stored in out[frame 127]): plane index (n*2+g)*16 + t,
// each plane kPlane floats. Total = 256 planes = exactly one output frame.

// K1: gate = tanh(conv3d(relu(bn(x[:, :64])), groups=2) + b)
// Direct-conv, NO LDS / barriers / atomics. Thread = one aligned 4-px strip;
// grid 784 blocks x 256 = 200,704 threads = 256 planes x 784 strips exactly.
// Per (ic): load BN params + 27 weights into regs; per (kd,kh) row: one
// aligned float4 + 2 scalar halo loads (L1/L2-hot; plane slice = 12.5 KB),
// BN+ReLU in regs, 12 FMAs. acc[4] carries the full 96-slice reduction;
// tanh+bias fused into the final float4 store. Padding = post-BN zero:
// invalid rows/cols contribute exactly 0 (halo skipped, never BN(0)).
__global__ __launch_bounds__(256)
void gate_conv_kernel(const float* __restrict__ x,
                      const float* __restrict__ gamma,
                      const float* __restrict__ beta,
                      const float* __restrict__ mean,
                      const float* __restrict__ var,
                      const float* __restrict__ cw,
                      const float* __restrict__ cb,
                      float* __restrict__ gate) {
  const int gid = blockIdx.x * 256 + threadIdx.x;   // 0..200703
  const int plane = gid / 784;                       // (n*2+g)*16 + t
  const int strip = gid - plane * 784;
  const int t = plane & 15;
  const int gg = (plane >> 4) & 1;
  const int n = plane >> 5;
  const int row = strip / 14;                        // 0..55
  const int w0 = (strip - row * 14) * 4;             // 0,4,...,52

  float acc[4] = {0.f, 0.f, 0.f, 0.f};

  for (int ic = 0; ic < 32; ++ic) {
    const int ch = gg * 32 + ic;
    const float sc = gamma[ch] * rsqrtf(var[ch] + 1e-5f);
    const float sh = beta[ch] - mean[ch] * sc;
    const float* wp = cw + ch * 27;
    float wk[27];
    #pragma unroll
    for (int j = 0; j < 27; ++j) wk[j] = wp[j];

    #pragma unroll
    for (int kd = 0; kd < 3; ++kd) {
      const int tt = t + kd - 1;
      if ((unsigned)tt >= (unsigned)kT) continue;    // temporal zero-pad
      const float* base = x + ((size_t)(n * kT + tt) * kCAll + ch) * kPlane;
      #pragma unroll
      for (int kh = 0; kh < 3; ++kh) {
        const int gr = row + kh - 1;
        if ((unsigned)gr >= (unsigned)kH) continue;  // vertical zero-pad
        const float* rp = base + gr * kW + w0;
        const float4 m = *(const float4*)rp;
        const float lraw = (w0 > 0) ? rp[-1] : 0.f;
        const float rraw = (w0 < 52) ? rp[4] : 0.f;
        float av[6];
        av[0] = (w0 > 0) ? fmaxf(0.f, fmaf(lraw, sc, sh)) : 0.f;
        av[1] = fmaxf(0.f, fmaf(m.x, sc, sh));
        av[2] = fmaxf(0.f, fmaf(m.y, sc, sh));
        av[3] = fmaxf(0.f, fmaf(m.z, sc, sh));
        av[4] = fmaxf(0.f, fmaf(m.w, sc, sh));
        av[5] = (w0 < 52) ? fmaxf(0.f, fmaf(rraw, sc, sh)) : 0.f;
        const float* wr = wk + kd * 9 + kh * 3;
        #pragma unroll
        for (int p = 0; p < 4; ++p)
          acc[p] = fmaf(av[p], wr[0],
                   fmaf(av[p + 1], wr[1], fmaf(av[p + 2], wr[2], acc[p])));
      }
    }
  }

  const float bias = cb[gg];
  float* gp = gate + (size_t)plane * kPlane + row * kW + w0;
  float4 o;
  o.x = tanhf(acc[0] + bias);
  o.y = tanhf(acc[1] + bias);
  o.z = tanhf(acc[2] + bias);
  o.w = tanhf(acc[3] + bias);
  *(float4*)gp = o;
}

// K1.5: copy the 3 gate planes frame-127 outputs need (g0[n7,t15]=239,
// g1[n7,t14]=254, g1[n7,t15]=255) into hole H = frame 126, channels 64..66.
__global__ __launch_bounds__(256)
void copy_gate_slice_kernel(float4* __restrict__ o4) {
  const int j = blockIdx.x * 256 + threadIdx.x;
  if (j >= 3 * kPlane4) return;
  const int q = j / kPlane4;
  const int rr = j - q * kPlane4;
  const int pidx = (q == 0) ? 239 : (q == 1 ? 254 : 255);
  const size_t G1 = (size_t)127 * kCAll * kPlane4;
  const size_t H = ((size_t)126 * kCAll + 64) * kPlane4;
  o4[H + j] = o4[G1 + (size_t)pidx * kPlane4 + rr];
}

// K2: frames 0..126. c>=64 passthrough (skip hole H); c<64 gated shift.
//   half0 (left):  out[t] = g0[t+1]*x[t+1] + x[t] - g0[t]*x[t]
//   half1 (right): out[t] = g1[t-1]*x[t-1] + x[t] - g1[t]*x[t]
//   channel regroup inverse: out k -> pre channel (k&1)*16 + (k>>1)
__global__ __launch_bounds__(256)
void shift_main_kernel(const float4* __restrict__ x4,
                       const float4* __restrict__ g4,
                       float4* __restrict__ o4) {
  const size_t total = (size_t)127 * kCAll * kPlane4;
  const size_t idx = (size_t)blockIdx.x * 256 + threadIdx.x;
  if (idx >= total) return;

  const int p = (int)(idx % kPlane4);
  const size_t rest = idx / kPlane4;
  const int c = (int)(rest % kCAll);
  const int f = (int)(rest / kCAll);

  if (c >= 64) {
    if (f == 126 && c <= 66) return;  // hole H holds gate slice until K3
    o4[idx] = x4[idx];
    return;
  }

  const int n = f >> 4;
  const int t = f & 15;
  const int half = c >> 5;
  const int k = c & 31;
  const int m = ((k & 1) << 4) + (k >> 1);
  const int src_ch = half * 32 + m;

  const size_t xcur = ((size_t)f * kCAll + src_ch) * kPlane4 + p;
  const size_t gbase = (size_t)(n * 2 + half) * kT * kPlane4 + p;

  const float4 xc = x4[xcur];
  const float4 gc = g4[gbase + (size_t)t * kPlane4];
  float4 y = make_float4(0.f, 0.f, 0.f, 0.f);
  if (half == 0) {
    if (t < kT - 1) {
      const float4 xn = x4[xcur + (size_t)kCAll * kPlane4];
      const float4 gn = g4[gbase + (size_t)(t + 1) * kPlane4];
      y.x = gn.x * xn.x; y.y = gn.y * xn.y; y.z = gn.z * xn.z; y.w = gn.w * xn.w;
    }
  } else {
    if (t > 0) {
      const float4 xp = x4[xcur - (size_t)kCAll * kPlane4];
      const float4 gp = g4[gbase + (size_t)(t - 1) * kPlane4];
      y.x = gp.x * xp.x; y.y = gp.y * xp.y; y.z = gp.z * xp.z; y.w = gp.w * xp.w;
    }
  }
  float4 res;
  res.x = y.x + (xc.x - gc.x * xc.x);
  res.y = y.y + (xc.y - gc.y * xc.y);
  res.z = y.z + (xc.z - gc.z * xc.z);
  res.w = y.w + (xc.w - gc.w * xc.w);
  o4[idx] = res;
}

// K3: frame 127 (n=7, t=15). Reads gate slices from hole H; overwrites the
// old gate region (frame 127) with final outputs.
__global__ __launch_bounds__(256)
void last_frame_kernel(const float4* __restrict__ x4,
                       float4* o4) {
  const int idx = blockIdx.x * 256 + threadIdx.x;
  if (idx >= kCAll * kPlane4) return;
  const size_t F127 = (size_t)127 * kCAll * kPlane4;
  const int p = idx % kPlane4;
  const int c = idx / kPlane4;
  if (c >= 64) { o4[F127 + idx] = x4[F127 + idx]; return; }

  const size_t H = ((size_t)126 * kCAll + 64) * kPlane4;
  const int half = c >> 5;
  const int k = c & 31;
  const int m = ((k & 1) << 4) + (k >> 1);
  const int src_ch = half * 32 + m;

  const float4 xc = x4[F127 + (size_t)src_ch * kPlane4 + p];
  float4 gc;
  float4 y = make_float4(0.f, 0.f, 0.f, 0.f);
  if (half == 0) {
    gc = o4[H + 0 * kPlane4 + p];                 // g0[t=15]; t+1 padded -> y=0
  } else {
    gc = o4[H + 2 * kPlane4 + p];                 // g1[t=15]
    const float4 gp = o4[H + 1 * kPlane4 + p];    // g1[t=14]
    const float4 xp = x4[((size_t)126 * kCAll + src_ch) * kPlane4 + p];
    y.x = gp.x * xp.x; y.y = gp.y * xp.y; y.z = gp.z * xp.z; y.w = gp.w * xp.w;
  }
  float4 res;
  res.x = y.x + (xc.x - gc.x * xc.x);
  res.y = y.y + (xc.y - gc.y * xc.y);
  res.z = y.z + (xc.z - gc.z * xc.z);
  res.w = y.w + (xc.w - gc.w * xc.w);
  o4[F127 + idx] = res;
}

// K4: hole H gets its real passthrough values.
__global__ __launch_bounds__(256)
void fix_hole_kernel(const float4* __restrict__ x4, float4* __restrict__ o4) {
  const int j = blockIdx.x * 256 + threadIdx.x;
  if (j >= 3 * kPlane4) return;
  const size_t H = ((size_t)126 * kCAll + 64) * kPlane4;
  o4[H + j] = x4[H + j];
}

extern "C" void kernel_launch(void* const* d_in, const int* in_sizes, int n_in,
                              void* d_out, int out_size, void* d_ws, size_t ws_size,
                              hipStream_t stream) {
  const float* x     = (const float*)d_in[0];
  const float* gamma = (const float*)d_in[1];
  const float* beta  = (const float*)d_in[2];
  const float* mean  = (const float*)d_in[3];
  const float* var   = (const float*)d_in[4];
  const float* cw    = (const float*)d_in[5];
  const float* cb    = (const float*)d_in[6];
  float* out = (float*)d_out;

  // Gate tensor lives in the frame-127 region of the output (exactly 1 frame).
  float* gate = out + (size_t)127 * kCAll * kPlane;

  // 256 planes x 784 strips = 200,704 threads = 784 blocks x 256 exactly.
  gate_conv_kernel<<<784, 256, 0, stream>>>(x, gamma, beta, mean, var, cw, cb, gate);
  copy_gate_slice_kernel<<<10, 256, 0, stream>>>((float4*)out);

  const size_t total4 = (size_t)127 * kCAll * kPlane4;  // 25,489,408
  shift_main_kernel<<<(unsigned)((total4 + 255) / 256), 256, 0, stream>>>(
      (const float4*)x, (const float4*)gate, (float4*)out);

  last_frame_kernel<<<(kCAll * kPlane4 + 255) / 256, 256, 0, stream>>>(
      (const float4*)x, (float4*)out);
  fix_hole_kernel<<<10, 256, 0, stream>>>((const float4*)x, (float4*)out);
}

// Round 11
// 224.906 us; speedup vs baseline: 1.4851x; 1.4851x over previous
//
#include <hip/hip_runtime.h>
#include <math.h>

namespace {
constexpr int kT = 16;
constexpr int kH = 56;
constexpr int kW = 56;
constexpr int kCAll = 256;
constexpr int kPlane = kH * kW;      // 3136
constexpr int kPlane4 = kPlane / 4;  // 784
}

// Gate layout (fp32, stored in out[frame 127]): plane index (n*2+g)*16 + t,
// each plane kPlane floats. Total = 256 planes = exactly one output frame.

// K1: gate = tanh(conv3d(relu(bn(x[:, :64])), groups=2) + b)
// Grid 512 = (n:8, t:16, g:2, stripe:2); block = 256 threads = 4 waves.
// Wave w owns ic = w*8..w*8+7 (x kd=3 -> 24 slices), staged into a
// WAVE-PRIVATE LDS buffer [30 rows][17 float4] -- ODD stride 17 makes
// bank-group = (row+slot) mod 8: distinct within every 16-lane quarter
// (worst 2-way = free), so NO XOR swizzle and no conflicts. Slice loads
// are register double-buffered (A/B, static indexing) so slice s+1's HBM
// latency hides under slice s's LDS+FMA. Layout: col c -> float c+4
// (slot 1..14 aligned b128 writes); slots 0/15 stay zero = col halo.
// Lane (r=lane>>1, h=lane&1) computes 28 px of row h0+r, cols 28h..28h+27.
// Final: 4 wave-partials reduced via LDS, tanh+bias fused. No atomics.
__global__ __launch_bounds__(256, 2)
void gate_conv_kernel(const float* __restrict__ x,
                      const float* __restrict__ gamma,
                      const float* __restrict__ beta,
                      const float* __restrict__ mean,
                      const float* __restrict__ var,
                      const float* __restrict__ cw,
                      const float* __restrict__ cb,
                      float* __restrict__ gate) {
  __shared__ float4 smb[4 * 510];      // 4 waves x (30 rows x 17 f4)

  const int bid = blockIdx.x;          // (((n*16+t)*2+g)*2+stripe)
  const int stripe = bid & 1;
  const int g = (bid >> 1) & 1;
  const int t = (bid >> 2) & 15;
  const int n = bid >> 6;              // 0..7
  const int h0 = stripe * 28;
  const int tid = threadIdx.x;
  const int wid = tid >> 6;            // wave 0..3
  const int lane = tid & 63;
  const int r = lane >> 1;             // 0..31 (active < 28)
  const int h = lane & 1;              // column half
  const int wbase = wid * 510;         // wave LDS base (float4 units)

  // Wave-private zero init: halo (rows w/o data, slots 0/15, pad 16) stays 0.
  for (int i = lane; i < 510; i += 64)
    smb[wbase + i] = make_float4(0.f, 0.f, 0.f, 0.f);

  // Staging map: 420 items = 30 rows x 14 data-f4; up to 7 per lane.
  int rr_u[7], fb_u[7], go_u[7];
  bool val_u[7];
  #pragma unroll
  for (int u = 0; u < 7; ++u) {
    const int j = lane + u * 64;
    bool v = (j < 420);
    int rr = 0, fb = 0, go = 0;
    if (v) {
      rr = j / 14;
      fb = j - rr * 14;
      const int gr = h0 + rr - 1;
      v = ((unsigned)gr < (unsigned)kH);
      if (v) go = gr * 14 + fb;
    }
    rr_u[u] = rr; fb_u[u] = fb; go_u[u] = go; val_u[u] = v;
  }

  float acc[28];
  #pragma unroll
  for (int p = 0; p < 28; ++p) acc[p] = 0.f;

  // Slice s (0..23): il = s/3, kd = s%3, ch = g*32 + wid*8 + il.
  auto loadS = [&](int s, float4 (&pf)[7]) {
    const int il = s / 3;
    const int kd = s - il * 3;
    const int tt = t + kd - 1;
    const int ch = g * 32 + wid * 8 + il;
    if (tt >= 0 && tt < kT) {
      const float4* src4 =
          (const float4*)x + ((size_t)(n * kT + tt) * kCAll + ch) * kPlane4;
      #pragma unroll
      for (int u = 0; u < 7; ++u)
        pf[u] = val_u[u] ? src4[go_u[u]] : make_float4(0.f, 0.f, 0.f, 0.f);
    } else {
      #pragma unroll
      for (int u = 0; u < 7; ++u) pf[u] = make_float4(0.f, 0.f, 0.f, 0.f);
    }
  };

  auto stageS = [&](int s, const float4 (&pf)[7]) {
    const int il = s / 3;
    const int kd = s - il * 3;
    const int tt = t + kd - 1;
    if (tt < 0 || tt >= kT) return;              // block-uniform skip
    const int ch = g * 32 + wid * 8 + il;
    const float sc = gamma[ch] * rsqrtf(var[ch] + 1e-5f);
    const float sh = beta[ch] - mean[ch] * sc;
    #pragma unroll
    for (int u = 0; u < 7; ++u) {
      if (val_u[u]) {
        float4 a = pf[u];
        a.x = fmaxf(0.f, fmaf(a.x, sc, sh));
        a.y = fmaxf(0.f, fmaf(a.y, sc, sh));
        a.z = fmaxf(0.f, fmaf(a.z, sc, sh));
        a.w = fmaxf(0.f, fmaf(a.w, sc, sh));
        smb[wbase + rr_u[u] * 17 + fb_u[u] + 1] = a;
      }
    }
  };

  auto computeS = [&](int s) {
    const int il = s / 3;
    const int kd = s - il * 3;
    const int tt = t + kd - 1;
    if (tt < 0 || tt >= kT) return;              // block-uniform skip
    if (r >= 28) return;
    const int ch = g * 32 + wid * 8 + il;
    const float* wbp = cw + ch * 27 + kd * 9;
    float wk[9];
    #pragma unroll
    for (int j = 0; j < 9; ++j) wk[j] = wbp[j];
    #pragma unroll
    for (int kh = 0; kh < 3; ++kh) {
      const int base = wbase + (r + kh) * 17 + 7 * h;   // slots 7h..7h+8
      float f[36];                                      // cols 28h-4..28h+31
      #pragma unroll
      for (int jj = 0; jj < 9; ++jj) {
        const float4 B = smb[base + jj];
        f[4 * jj + 0] = B.x; f[4 * jj + 1] = B.y;
        f[4 * jj + 2] = B.z; f[4 * jj + 3] = B.w;
      }
      const float w0 = wk[kh * 3 + 0];
      const float w1 = wk[kh * 3 + 1];
      const float w2 = wk[kh * 3 + 2];
      #pragma unroll
      for (int p = 0; p < 28; ++p)
        acc[p] = fmaf(f[p + 3], w0,
                 fmaf(f[p + 4], w1, fmaf(f[p + 5], w2, acc[p])));
    }
  };

  // Double-buffered pipeline over 24 slices (static A/B register sets).
  float4 A[7], B[7];
  loadS(0, A);
  for (int s2 = 0; s2 < 24; s2 += 2) {
    if (s2 + 1 < 24) loadS(s2 + 1, B);
    stageS(s2, A);
    computeS(s2);
    if (s2 + 2 < 24) loadS(s2 + 2, A);
    if (s2 + 1 < 24) { stageS(s2 + 1, B); computeS(s2 + 1); }
  }

  // Cross-wave reduction: reuse smb as float region [4][1568].
  __syncthreads();                               // all waves' compute done
  float* smf = (float*)smb;
  if (r < 28) {
    const int q0 = r * 56 + h * 28;
    #pragma unroll
    for (int p = 0; p < 28; ++p) smf[wid * 1568 + q0 + p] = acc[p];
  }
  __syncthreads();
  const float bias = cb[g];
  float* gp = gate + ((size_t)(n * 2 + g) * kT + t) * kPlane + h0 * kW;
  for (int q = tid; q < 1568; q += 256) {
    float s = smf[q] + smf[1568 + q] + smf[2 * 1568 + q] + smf[3 * 1568 + q];
    gp[q] = tanhf(s + bias);
  }
}

// K1.5: copy the 3 gate planes frame-127 outputs need (g0[n7,t15]=239,
// g1[n7,t14]=254, g1[n7,t15]=255) into hole H = frame 126, channels 64..66.
__global__ __launch_bounds__(256)
void copy_gate_slice_kernel(float4* __restrict__ o4) {
  const int j = blockIdx.x * 256 + threadIdx.x;
  if (j >= 3 * kPlane4) return;
  const int q = j / kPlane4;
  const int rr = j - q * kPlane4;
  const int pidx = (q == 0) ? 239 : (q == 1 ? 254 : 255);
  const size_t G1 = (size_t)127 * kCAll * kPlane4;
  const size_t H = ((size_t)126 * kCAll + 64) * kPlane4;
  o4[H + j] = o4[G1 + (size_t)pidx * kPlane4 + rr];
}

// K2: frames 0..126. c>=64 passthrough (skip hole H); c<64 gated shift.
//   half0 (left):  out[t] = g0[t+1]*x[t+1] + x[t] - g0[t]*x[t]
//   half1 (right): out[t] = g1[t-1]*x[t-1] + x[t] - g1[t]*x[t]
//   channel regroup inverse: out k -> pre channel (k&1)*16 + (k>>1)
__global__ __launch_bounds__(256)
void shift_main_kernel(const float4* __restrict__ x4,
                       const float4* __restrict__ g4,
                       float4* __restrict__ o4) {
  const size_t total = (size_t)127 * kCAll * kPlane4;
  const size_t idx = (size_t)blockIdx.x * 256 + threadIdx.x;
  if (idx >= total) return;

  const int p = (int)(idx % kPlane4);
  const size_t rest = idx / kPlane4;
  const int c = (int)(rest % kCAll);
  const int f = (int)(rest / kCAll);

  if (c >= 64) {
    if (f == 126 && c <= 66) return;  // hole H holds gate slice until K3
    o4[idx] = x4[idx];
    return;
  }

  const int n = f >> 4;
  const int t = f & 15;
  const int half = c >> 5;
  const int k = c & 31;
  const int m = ((k & 1) << 4) + (k >> 1);
  const int src_ch = half * 32 + m;

  const size_t xcur = ((size_t)f * kCAll + src_ch) * kPlane4 + p;
  const size_t gbase = (size_t)(n * 2 + half) * kT * kPlane4 + p;

  const float4 xc = x4[xcur];
  const float4 gc = g4[gbase + (size_t)t * kPlane4];
  float4 y = make_float4(0.f, 0.f, 0.f, 0.f);
  if (half == 0) {
    if (t < kT - 1) {
      const float4 xn = x4[xcur + (size_t)kCAll * kPlane4];
      const float4 gn = g4[gbase + (size_t)(t + 1) * kPlane4];
      y.x = gn.x * xn.x; y.y = gn.y * xn.y; y.z = gn.z * xn.z; y.w = gn.w * xn.w;
    }
  } else {
    if (t > 0) {
      const float4 xp = x4[xcur - (size_t)kCAll * kPlane4];
      const float4 gp = g4[gbase + (size_t)(t - 1) * kPlane4];
      y.x = gp.x * xp.x; y.y = gp.y * xp.y; y.z = gp.z * xp.z; y.w = gp.w * xp.w;
    }
  }
  float4 res;
  res.x = y.x + (xc.x - gc.x * xc.x);
  res.y = y.y + (xc.y - gc.y * xc.y);
  res.z = y.z + (xc.z - gc.z * xc.z);
  res.w = y.w + (xc.w - gc.w * xc.w);
  o4[idx] = res;
}

// K3: frame 127 (n=7, t=15). Reads gate slices from hole H; overwrites the
// old gate region (frame 127) with final outputs.
__global__ __launch_bounds__(256)
void last_frame_kernel(const float4* __restrict__ x4,
                       float4* o4) {
  const int idx = blockIdx.x * 256 + threadIdx.x;
  if (idx >= kCAll * kPlane4) return;
  const size_t F127 = (size_t)127 * kCAll * kPlane4;
  const int p = idx % kPlane4;
  const int c = idx / kPlane4;
  if (c >= 64) { o4[F127 + idx] = x4[F127 + idx]; return; }

  const size_t H = ((size_t)126 * kCAll + 64) * kPlane4;
  const int half = c >> 5;
  const int k = c & 31;
  const int m = ((k & 1) << 4) + (k >> 1);
  const int src_ch = half * 32 + m;

  const float4 xc = x4[F127 + (size_t)src_ch * kPlane4 + p];
  float4 gc;
  float4 y = make_float4(0.f, 0.f, 0.f, 0.f);
  if (half == 0) {
    gc = o4[H + 0 * kPlane4 + p];                 // g0[t=15]; t+1 padded -> y=0
  } else {
    gc = o4[H + 2 * kPlane4 + p];                 // g1[t=15]
    const float4 gp = o4[H + 1 * kPlane4 + p];    // g1[t=14]
    const float4 xp = x4[((size_t)126 * kCAll + src_ch) * kPlane4 + p];
    y.x = gp.x * xp.x; y.y = gp.y * xp.y; y.z = gp.z * xp.z; y.w = gp.w * xp.w;
  }
  float4 res;
  res.x = y.x + (xc.x - gc.x * xc.x);
  res.y = y.y + (xc.y - gc.y * xc.y);
  res.z = y.z + (xc.z - gc.z * xc.z);
  res.w = y.w + (xc.w - gc.w * xc.w);
  o4[F127 + idx] = res;
}

// K4: hole H gets its real passthrough values.
__global__ __launch_bounds__(256)
void fix_hole_kernel(const float4* __restrict__ x4, float4* __restrict__ o4) {
  const int j = blockIdx.x * 256 + threadIdx.x;
  if (j >= 3 * kPlane4) return;
  const size_t H = ((size_t)126 * kCAll + 64) * kPlane4;
  o4[H + j] = x4[H + j];
}

extern "C" void kernel_launch(void* const* d_in, const int* in_sizes, int n_in,
                              void* d_out, int out_size, void* d_ws, size_t ws_size,
                              hipStream_t stream) {
  const float* x     = (const float*)d_in[0];
  const float* gamma = (const float*)d_in[1];
  const float* beta  = (const float*)d_in[2];
  const float* mean  = (const float*)d_in[3];
  const float* var   = (const float*)d_in[4];
  const float* cw    = (const float*)d_in[5];
  const float* cb    = (const float*)d_in[6];
  float* out = (float*)d_out;

  // Gate tensor lives in the frame-127 region of the output (exactly 1 frame).
  float* gate = out + (size_t)127 * kCAll * kPlane;

  // 8 n * 16 t * 2 g * 2 stripes = 512 blocks, 256 threads (4 waves)
  gate_conv_kernel<<<512, 256, 0, stream>>>(x, gamma, beta, mean, var, cw, cb, gate);
  copy_gate_slice_kernel<<<10, 256, 0, stream>>>((float4*)out);

  const size_t total4 = (size_t)127 * kCAll * kPlane4;  // 25,489,408
  shift_main_kernel<<<(unsigned)((total4 + 255) / 256), 256, 0, stream>>>(
      (const float4*)x, (const float4*)gate, (float4*)out);

  last_frame_kernel<<<(kCAll * kPlane4 + 255) / 256, 256, 0, stream>>>(
      (const float4*)x, (float4*)out);
  fix_hole_kernel<<<10, 256, 0, stream>>>((const float4*)x, (float4*)out);
}